// Round 1
// baseline (1118.859 us; speedup 1.0000x reference)
//
#include <hip/hip_runtime.h>
#include <hip/hip_bf16.h>

// QuantizedLinear: out[b,s,o] = sum_i x[b,s,i] * (code[q[o,i]] * absmax[o]) + bias[o]
// M = 2*2048 = 4096, K = 4096, N = 16384. absmax index == o because in_features == BLOCK.
//
// Path: dequant W -> bf16 (ws), convert x -> bf16 (ws), then m97-structure bf16 MFMA
// GEMM (C = A @ W^T + bias) with global_load_lds(16B) staging.

typedef __bf16 bf16x8 __attribute__((ext_vector_type(8)));
typedef __bf16 bf16x4 __attribute__((ext_vector_type(4)));
typedef float  f32x4  __attribute__((ext_vector_type(4)));

#define GLD_LDS(gp, lp) \
    __builtin_amdgcn_global_load_lds((const __attribute__((address_space(1))) void*)(gp), \
                                     (__attribute__((address_space(3))) void*)(lp), 16, 0, 0)

static constexpr int M = 4096;
static constexpr int N = 16384;
static constexpr int K = 4096;
static constexpr int BM = 128;
static constexpr int BN = 128;
static constexpr int BK = 32;

// ---------------------------------------------------------------- dequant W
// W_bf16[o*K + i] = bf16(code[q[o*K+i]] * absmax[o]); 4 elems/thread.
__global__ __launch_bounds__(256) void dequant_w(const int4* __restrict__ q4,
                                                 const float* __restrict__ code,
                                                 const float* __restrict__ absmax,
                                                 bf16x4* __restrict__ W)
{
    unsigned gid = blockIdx.x * 256u + threadIdx.x;     // 16M threads, 4 elems each
    int4 qv = q4[gid];
    float am = absmax[gid >> 10];                       // (gid*4) / 4096
    bf16x4 w;
    w[0] = (__bf16)(code[qv.x] * am);
    w[1] = (__bf16)(code[qv.y] * am);
    w[2] = (__bf16)(code[qv.z] * am);
    w[3] = (__bf16)(code[qv.w] * am);
    W[gid] = w;
}

// ---------------------------------------------------------------- x fp32 -> bf16
__global__ __launch_bounds__(256) void cvt_x(const float4* __restrict__ x,
                                             bf16x4* __restrict__ xb)
{
    unsigned gid = blockIdx.x * 256u + threadIdx.x;     // 4M threads
    float4 v = x[gid];
    bf16x4 o;
    o[0] = (__bf16)v.x;
    o[1] = (__bf16)v.y;
    o[2] = (__bf16)v.z;
    o[3] = (__bf16)v.w;
    xb[gid] = o;
}

// ---------------------------------------------------------------- GEMM C = A @ B^T + bias
// A: M x K bf16 row-major. B: N x K bf16 row-major (= W). C: M x N fp32.
// 256 threads = 4 waves (2x2), each wave owns a 64x64 sub-tile (4x4 of 16x16x32 MFMA).
__global__ __launch_bounds__(256) void gemm_bt_bias(const __bf16* __restrict__ A,
                                                    const __bf16* __restrict__ B,
                                                    const float* __restrict__ bias,
                                                    float* __restrict__ C)
{
    // NO padding: global_load_lds dest is wave-uniform base + lane*16 — layout must
    // be exactly contiguous in lane order.
    __shared__ __bf16 As[BM * BK];   // [m][k] row-major, 8 KB
    __shared__ __bf16 Bs[BN * BK];   // [n][k] row-major, 8 KB

    const int tid  = threadIdx.x;
    const int lane = tid & 63;
    const int wave = tid >> 6;
    const int bm = blockIdx.y * BM;
    const int bn = blockIdx.x * BN;
    const int wm = (wave >> 1) * 64;
    const int wn = (wave & 1) * 64;

    // staging map: thread t covers row t/4 (0..63), k-cols (t%4)*8..+8 of the tile;
    // LDS byte offset = t*16 (wave base w*1024 + lane*16 — contiguous per wave).
    const int srow = tid >> 2;
    const int skcol = (tid & 3) * 8;

    const __bf16* ag0 = A + (long long)(bm + srow) * K + skcol;
    const __bf16* bg0 = B + (long long)(bn + srow) * K + skcol;

    f32x4 acc[4][4] = {};

    const int fr = lane & 15;          // fragment row within 16
    const int fk = (lane >> 4) * 8;    // fragment k offset

    for (int k0 = 0; k0 < K; k0 += BK) {
        __syncthreads();   // previous iteration's ds_reads done before overwrite
        GLD_LDS(ag0 + k0,            As + tid * 8);          // rows 0..63
        GLD_LDS(ag0 + k0 + 64 * K,   As + 2048 + tid * 8);   // rows 64..127
        GLD_LDS(bg0 + k0,            Bs + tid * 8);
        GLD_LDS(bg0 + k0 + 64 * K,   Bs + 2048 + tid * 8);
        __syncthreads();   // compiler drains vmcnt before s_barrier

        bf16x8 af[4], bfr[4];
#pragma unroll
        for (int i = 0; i < 4; ++i)
            af[i] = *(const bf16x8*)(As + (wm + i * 16 + fr) * BK + fk);
#pragma unroll
        for (int i = 0; i < 4; ++i)
            bfr[i] = *(const bf16x8*)(Bs + (wn + i * 16 + fr) * BK + fk);

#pragma unroll
        for (int mi = 0; mi < 4; ++mi)
#pragma unroll
            for (int ni = 0; ni < 4; ++ni)
                acc[mi][ni] = __builtin_amdgcn_mfma_f32_16x16x32_bf16(
                    af[mi], bfr[ni], acc[mi][ni], 0, 0, 0);
    }

    // epilogue: D[m=(lane>>4)*4+reg][n=lane&15] (verified m89/m91 mapping)
    const int cn = lane & 15;
    const int rq = (lane >> 4) * 4;
#pragma unroll
    for (int ni = 0; ni < 4; ++ni) {
        const int n = bn + wn + ni * 16 + cn;
        const float bv = bias[n];
#pragma unroll
        for (int mi = 0; mi < 4; ++mi) {
#pragma unroll
            for (int r = 0; r < 4; ++r) {
                const int m = bm + wm + mi * 16 + rq + r;
                C[(long long)m * N + n] = acc[mi][ni][r] + bv;
            }
        }
    }
}

extern "C" void kernel_launch(void* const* d_in, const int* in_sizes, int n_in,
                              void* d_out, int out_size, void* d_ws, size_t ws_size,
                              hipStream_t stream)
{
    const float* x      = (const float*)d_in[0];   // 2*2048*4096 fp32
    const int*   qw     = (const int*)d_in[1];     // 16384*4096 int32
    const float* absmax = (const float*)d_in[2];   // 16384 fp32
    const float* code   = (const float*)d_in[3];   // 256 fp32
    const float* bias   = (const float*)d_in[4];   // 16384 fp32
    float* out = (float*)d_out;                    // 4096 x 16384 fp32

    // workspace: W_bf16 (N*K*2 = 128 MB) then x_bf16 (M*K*2 = 32 MB)
    __bf16* Wb = (__bf16*)d_ws;
    __bf16* Xb = (__bf16*)((char*)d_ws + (size_t)N * K * sizeof(__bf16));

    // dequant: N*K/4 = 16M work-items
    dequant_w<<<(N * (long long)K) / 4 / 256, 256, 0, stream>>>(
        (const int4*)qw, code, absmax, (bf16x4*)Wb);

    // x convert: M*K/4 = 4M work-items
    cvt_x<<<(M * (long long)K) / 4 / 256, 256, 0, stream>>>(
        (const float4*)x, (bf16x4*)Xb);

    dim3 grid(N / BN, M / BM);   // 128 x 32 = 4096 blocks
    gemm_bt_bias<<<grid, 256, 0, stream>>>(Xb, Wb, bias, out);
}